// Round 4
// baseline (155.049 us; speedup 1.0000x reference)
//
#include <hip/hip_runtime.h>

#define B_   4
#define L_   2048
#define D_   256
#define H_   8
#define DH_  32
#define MLP_ 1024
#define LOG2E 1.4426950408889634f

typedef __attribute__((ext_vector_type(8))) short  short8;
typedef __attribute__((ext_vector_type(4))) float  f32x4;

union FragU { short8 v; struct { unsigned long long lo, hi; } q; unsigned u[4]; };

__device__ __forceinline__ unsigned short f2bf(float f) {
  unsigned u = __float_as_uint(f);
  u += 0x7fffu + ((u >> 16) & 1u);
  return (unsigned short)(u >> 16);
}

__device__ __forceinline__ unsigned long long pack4(float a, float b, float c, float d) {
  return (unsigned long long)f2bf(a) | ((unsigned long long)f2bf(b) << 16)
       | ((unsigned long long)f2bf(c) << 32) | ((unsigned long long)f2bf(d) << 48);
}

__device__ __forceinline__ unsigned cvt_pk_bf16(float lo, float hi) {
  unsigned r;
  asm("v_cvt_pk_bf16_f32 %0, %1, %2" : "=v"(r) : "v"(lo), "v"(hi));
  return r;
}

__device__ __forceinline__ float fexp2(float x) {
#if __has_builtin(__builtin_amdgcn_exp2f)
  return __builtin_amdgcn_exp2f(x);
#else
  return exp2f(x);
#endif
}

// global -> LDS direct, 16B/lane (LDS dest: wave-uniform base + lane*16B, linear)
#define GLL16(gp, lp) __builtin_amdgcn_global_load_lds( \
    (const __attribute__((address_space(1))) void*)(gp), \
    (__attribute__((address_space(3))) void*)(lp), 16, 0, 0)

// ---------------- converts ----------------

__global__ void cvt_k(const float* __restrict__ in, unsigned short* __restrict__ out, int n4) {
  const int i = blockIdx.x * blockDim.x + threadIdx.x;
  if (i < n4) {
    const float4 v = *(const float4*)(in + (size_t)i * 4);
    *(unsigned long long*)(out + (size_t)i * 4) = pack4(v.x, v.y, v.z, v.w);
  }
}

// all four weight transposes in one launch: out[c][r] = bf16(in[r][c])
__global__ void prep_w(const float* __restrict__ Wqkv, const float* __restrict__ Wo,
                       const float* __restrict__ W1, const float* __restrict__ W2,
                       unsigned short* __restrict__ wqkvt, unsigned short* __restrict__ wot,
                       unsigned short* __restrict__ w1t, unsigned short* __restrict__ w2t) {
  const int i = blockIdx.x * 256 + threadIdx.x;
  if (i < 196608) {            // Wqkv 256x768
    const int r = i / 768, c = i - r * 768;
    wqkvt[(size_t)c * 256 + r] = f2bf(Wqkv[i]);
  } else if (i < 262144) {     // Wo 256x256
    const int j = i - 196608, r = j >> 8, c = j & 255;
    wot[(size_t)c * 256 + r] = f2bf(Wo[j]);
  } else if (i < 524288) {     // W1 256x1024
    const int j = i - 262144, r = j >> 10, c = j & 1023;
    w1t[(size_t)c * 256 + r] = f2bf(W1[j]);
  } else {                     // W2 1024x256
    const int j = i - 524288, r = j >> 8, c = j & 255;
    w2t[(size_t)c * 1024 + r] = f2bf(W2[j]);
  }
}

// ---------------- GEMM (dbuf, counted vmcnt): C = A * Bt^T + bias ----------------
// MODE 0: qkv (scatter q/k -> [B,H,L,DH] (q scaled by DH^-.5*log2e), v -> [B,H,DH,L])
// MODE 2: mlp1 (relu -> bf16)
template <int MODE, int TM, int TN>
__launch_bounds__(256)
__global__ void gemm_k(const unsigned short* __restrict__ A,
                       const unsigned short* __restrict__ Bt,
                       const float* __restrict__ bias,
                       unsigned short* __restrict__ outb0,
                       unsigned short* __restrict__ outb1,
                       unsigned short* __restrict__ outb2,
                       int K)
{
  constexpr int MI = TM / 32, NI = TN / 32;
  __shared__ alignas(16) unsigned short As[2][TM * 64];
  __shared__ alignas(16) unsigned short Bs[2][TN * 64];
  const int tid  = threadIdx.x;
  const int lane = tid & 63, wv = tid >> 6;
  const int wr = wv >> 1, wc = wv & 1;
  const int lr = lane & 15, g = lane >> 4;
  const int m0 = blockIdx.y * TM, n0 = blockIdx.x * TN;
  const int l8 = lane >> 3, jj = lane & 7;

  auto stage = [&](int buf, int k0) {
#pragma unroll
    for (int i = 0; i < MI; ++i) {
      const int row = i * 32 + wv * 8 + l8;
      GLL16(A + (size_t)(m0 + row) * K + k0 + ((jj ^ (row & 7)) * 8),
            &As[buf][i * 2048 + wv * 512]);
    }
#pragma unroll
    for (int i = 0; i < NI; ++i) {
      const int row = i * 32 + wv * 8 + l8;
      GLL16(Bt + (size_t)(n0 + row) * K + k0 + ((jj ^ (row & 7)) * 8),
            &Bs[buf][i * 2048 + wv * 512]);
    }
  };

  f32x4 acc[MI][NI];
#pragma unroll
  for (int i = 0; i < MI; ++i)
#pragma unroll
    for (int j = 0; j < NI; ++j) acc[i][j] = (f32x4)(0.f);

  stage(0, 0);
  for (int k0 = 0; k0 < K; k0 += 64) {
    const int cur = (k0 >> 6) & 1;
    if (k0 + 64 < K) {
      stage(cur ^ 1, k0 + 64);
      asm volatile("s_waitcnt vmcnt(%0)" :: "n"(MI + NI) : "memory");
    } else {
      asm volatile("s_waitcnt vmcnt(0)" ::: "memory");
    }
    __builtin_amdgcn_sched_barrier(0);
    __builtin_amdgcn_s_barrier();
#pragma unroll
    for (int kk = 0; kk < 2; ++kk) {
      FragU af[MI], bf[NI];
#pragma unroll
      for (int mi = 0; mi < MI; ++mi) {
        const int row = wr * (TM / 2) + mi * 16 + lr;
        const int sw = (row & 7) << 3;
        af[mi].q.lo = *(const unsigned long long*)&As[cur][row * 64 + ((kk * 32 + 4 * g) ^ sw)];
        af[mi].q.hi = *(const unsigned long long*)&As[cur][row * 64 + ((kk * 32 + 16 + 4 * g) ^ sw)];
      }
#pragma unroll
      for (int ni = 0; ni < NI; ++ni) {
        const int row = wc * (TN / 2) + ni * 16 + lr;
        const int sw = (row & 7) << 3;
        bf[ni].q.lo = *(const unsigned long long*)&Bs[cur][row * 64 + ((kk * 32 + 4 * g) ^ sw)];
        bf[ni].q.hi = *(const unsigned long long*)&Bs[cur][row * 64 + ((kk * 32 + 16 + 4 * g) ^ sw)];
      }
#pragma unroll
      for (int mi = 0; mi < MI; ++mi)
#pragma unroll
        for (int ni = 0; ni < NI; ++ni)
          acc[mi][ni] = __builtin_amdgcn_mfma_f32_16x16x32_bf16(af[mi].v, bf[ni].v, acc[mi][ni], 0, 0, 0);
    }
    asm volatile("s_waitcnt lgkmcnt(0)" ::: "memory");
    __builtin_amdgcn_sched_barrier(0);
    __builtin_amdgcn_s_barrier();
  }

#pragma unroll
  for (int mi = 0; mi < MI; ++mi) {
#pragma unroll
    for (int ni = 0; ni < NI; ++ni) {
      const int n = n0 + wc * (TN / 2) + ni * 16 + lr;
      const float bv = bias[n];
#pragma unroll
      for (int r = 0; r < 4; ++r) {
        const int m = m0 + wr * (TM / 2) + mi * 16 + 4 * g + r;
        float val = acc[mi][ni][r] + bv;
        if constexpr (MODE == 0) {
          const int s = n >> 8, hh = (n >> 5) & 7, dh = n & 31;
          const int bb = m >> 11, l = m & (L_ - 1);
          if (s == 0) {
            outb0[((size_t)(bb * H_ + hh) * L_ + l) * DH_ + dh] =
                f2bf(val * (0.17677669529663687f * LOG2E));
          } else if (s == 1) {
            outb1[((size_t)(bb * H_ + hh) * L_ + l) * DH_ + dh] = f2bf(val);
          } else {
            outb2[((size_t)(bb * H_ + hh) * DH_ + dh) * L_ + l] = f2bf(val);
          }
        } else {
          outb0[(size_t)m * MLP_ + n] = f2bf(fmaxf(val, 0.f));
        }
      }
    }
  }
}

// ---------------- fused GEMM + residual + LayerNorm (full row TN=256) ----------------
// 512 threads: 8 waves (2 row-groups x 4 col-groups); TM=32 rows/block.
template <bool WRITE_BF>
__launch_bounds__(512)
__global__ void gemmln_k(const unsigned short* __restrict__ A,
                         const unsigned short* __restrict__ Bt,
                         const float* __restrict__ bias,
                         const float* __restrict__ resid,
                         const float* __restrict__ lng,
                         const float* __restrict__ lnb,
                         float* __restrict__ outf,
                         unsigned short* __restrict__ outb,
                         int K)
{
  __shared__ alignas(16) unsigned short As[2][32 * 64];
  __shared__ alignas(16) unsigned short Bs[2][256 * 64];
  __shared__ float rsum[8][16], rsq[8][16], rmu[32], rrstd[32];
  const int tid  = threadIdx.x;
  const int lane = tid & 63, wv = tid >> 6;
  const int wr = wv >> 2, wc = wv & 3;
  const int lr = lane & 15, g = lane >> 4;
  const int m0 = blockIdx.x * 32;
  const int l8 = lane >> 3, jj = lane & 7;

  auto stage = [&](int buf, int k0) {
    if (wv < 4) {
      const int row = wv * 8 + l8;
      GLL16(A + (size_t)(m0 + row) * K + k0 + ((jj ^ (row & 7)) * 8),
            &As[buf][wv * 512]);
    }
#pragma unroll
    for (int i = 0; i < 4; ++i) {
      const int n = i * 64 + wv * 8 + l8;
      GLL16(Bt + (size_t)n * K + k0 + ((jj ^ (n & 7)) * 8),
            &Bs[buf][i * 4096 + wv * 512]);
    }
  };

  f32x4 acc[4];
#pragma unroll
  for (int j = 0; j < 4; ++j) acc[j] = (f32x4)(0.f);

  stage(0, 0);
  for (int k0 = 0; k0 < K; k0 += 64) {
    const int cur = (k0 >> 6) & 1;
    if (k0 + 64 < K) {
      stage(cur ^ 1, k0 + 64);
      asm volatile("s_waitcnt vmcnt(4)" ::: "memory");   // min per-wave issue count (conservative)
    } else {
      asm volatile("s_waitcnt vmcnt(0)" ::: "memory");
    }
    __builtin_amdgcn_sched_barrier(0);
    __builtin_amdgcn_s_barrier();
#pragma unroll
    for (int kk = 0; kk < 2; ++kk) {
      FragU af, bf[4];
      {
        const int row = wr * 16 + lr;
        const int sw = (row & 7) << 3;
        af.q.lo = *(const unsigned long long*)&As[cur][row * 64 + ((kk * 32 + 4 * g) ^ sw)];
        af.q.hi = *(const unsigned long long*)&As[cur][row * 64 + ((kk * 32 + 16 + 4 * g) ^ sw)];
      }
#pragma unroll
      for (int ni = 0; ni < 4; ++ni) {
        const int row = wc * 64 + ni * 16 + lr;
        const int sw = (row & 7) << 3;
        bf[ni].q.lo = *(const unsigned long long*)&Bs[cur][row * 64 + ((kk * 32 + 4 * g) ^ sw)];
        bf[ni].q.hi = *(const unsigned long long*)&Bs[cur][row * 64 + ((kk * 32 + 16 + 4 * g) ^ sw)];
      }
#pragma unroll
      for (int ni = 0; ni < 4; ++ni)
        acc[ni] = __builtin_amdgcn_mfma_f32_16x16x32_bf16(af.v, bf[ni].v, acc[ni], 0, 0, 0);
    }
    asm volatile("s_waitcnt lgkmcnt(0)" ::: "memory");
    __builtin_amdgcn_sched_barrier(0);
    __builtin_amdgcn_s_barrier();
  }

  // epilogue: bias + resid, then in-block LayerNorm over the full 256-wide row
  float g4[4], b4[4], bias4[4];
  int col[4];
#pragma unroll
  for (int ni = 0; ni < 4; ++ni) {
    col[ni] = wc * 64 + ni * 16 + lr;
    g4[ni] = lng[col[ni]]; b4[ni] = lnb[col[ni]]; bias4[ni] = bias[col[ni]];
  }
  float vals[4][4];                        // [ni][r]
#pragma unroll
  for (int r = 0; r < 4; ++r) {
    const int row = wr * 16 + 4 * g + r;
    float s = 0.f, q = 0.f;
#pragma unroll
    for (int ni = 0; ni < 4; ++ni) {
      float v = acc[ni][r] + bias4[ni] + resid[(size_t)(m0 + row) * D_ + col[ni]];
      vals[ni][r] = v; s += v; q += v * v;
    }
#pragma unroll
    for (int off = 1; off < 16; off <<= 1) {
      s += __shfl_xor(s, off); q += __shfl_xor(q, off);
    }
    if (lr == 0) { rsum[wv][4 * g + r] = s; rsq[wv][4 * g + r] = q; }
  }
  __syncthreads();
  if (tid < 32) {
    const int base = (tid >> 4) * 4, rr = tid & 15;
    const float s = rsum[base][rr] + rsum[base + 1][rr] + rsum[base + 2][rr] + rsum[base + 3][rr];
    const float q = rsq[base][rr] + rsq[base + 1][rr] + rsq[base + 2][rr] + rsq[base + 3][rr];
    const float mu = s * (1.f / D_);
    rmu[tid] = mu;
    rrstd[tid] = rsqrtf(q * (1.f / D_) - mu * mu + 1e-5f);
  }
  __syncthreads();
#pragma unroll
  for (int r = 0; r < 4; ++r) {
    const int row = wr * 16 + 4 * g + r;
    const float mu = rmu[row], rs = rrstd[row];
#pragma unroll
    for (int ni = 0; ni < 4; ++ni) {
      const float o = (vals[ni][r] - mu) * rs * g4[ni] + b4[ni];
      const size_t idx = (size_t)(m0 + row) * D_ + col[ni];
      outf[idx] = o;
      if constexpr (WRITE_BF) outb[idx] = f2bf(o);
    }
  }
}

// ---------------- flash attention (2-phase dbuf pipeline) ----------------
__launch_bounds__(256)
__global__ void attn_k(const unsigned short* __restrict__ qb,
                       const unsigned short* __restrict__ kb,
                       const unsigned short* __restrict__ vT,
                       const int* __restrict__ mask,
                       const float* __restrict__ relb,
                       unsigned short* __restrict__ aout)
{
  __shared__ alignas(16) unsigned short Ks[2][64 * 40];
  __shared__ alignas(16) unsigned short Vs[2][32 * 64];
  __shared__ alignas(16) float biasv[36];
  __shared__ alignas(16) float maskadd[2][64];
  const int tid = threadIdx.x;
  const int lane = tid & 63, wv = tid >> 6;
  const int lr = lane & 15, g = lane >> 4;
  const int bh = blockIdx.y, b = bh >> 3, h = bh & 7;
  const size_t bhoff = (size_t)bh * (L_ * DH_);
  if (tid < 33) biasv[tid] = relb[tid * H_ + h] * LOG2E;
  const float bias_lo = relb[h] * LOG2E;
  const float bias_hi = relb[32 * H_ + h] * LOG2E;
  const int qw0 = blockIdx.x * 64 + wv * 16;

  FragU qf;
  {
    const unsigned short* qr = qb + bhoff + (size_t)(qw0 + lr) * DH_;
    qf.q.lo = *(const unsigned long long*)(qr + 4 * g);
    qf.q.hi = *(const unsigned long long*)(qr + 16 + 4 * g);
  }
  f32x4 O0 = (f32x4)(0.f), O1 = (f32x4)(0.f);
  float m_run = -1e30f, ssum = 0.f;
  const f32x4 z4 = (f32x4)(0.f);
  const int krow = tid >> 2, kc8 = tid & 3;
  const int vrow = wv * 8 + (lane >> 3), vjj = lane & 7;

  // prologue: stage chunk 0 into buffer 0
  {
    int4 kreg = *(const int4*)(kb + bhoff + (size_t)krow * DH_ + kc8 * 8);
    GLL16(vT + ((size_t)bh * DH_ + vrow) * L_ + ((vjj ^ (vrow & 7)) * 8), &Vs[0][wv * 512]);
    int mreg = (tid < 64) ? mask[b * L_ + tid] : 0;
    *(int4*)&Ks[0][krow * 40 + kc8 * 8] = kreg;
    if (tid < 64) maskadd[0][tid] = mreg ? -1e9f : 0.f;
  }
  __syncthreads();

  for (int ch = 0; ch < 32; ++ch) {
    const int cur = ch & 1, nxt = cur ^ 1;
    const int kvbase = ch * 64;
    const bool more = (ch + 1 < 32);
    int4 kreg = {0, 0, 0, 0};
    int mreg = 0;
    if (more) {
      kreg = *(const int4*)(kb + bhoff + (size_t)(kvbase + 64 + krow) * DH_ + kc8 * 8);
      GLL16(vT + ((size_t)bh * DH_ + vrow) * L_ + kvbase + 64 + ((vjj ^ (vrow & 7)) * 8),
            &Vs[nxt][wv * 512]);
      if (tid < 64) mreg = mask[b * L_ + kvbase + 64 + tid];
    }

    // ---- compute chunk ch from buffers[cur] ----
    FragU kf[4];
#pragma unroll
    for (int jt = 0; jt < 4; ++jt) {
      const int base = (jt * 16 + lr) * 40;
      kf[jt].q.lo = *(const unsigned long long*)&Ks[cur][base + 4 * g];
      kf[jt].q.hi = *(const unsigned long long*)&Ks[cur][base + 16 + 4 * g];
    }
    FragU vf[2][2];
#pragma unroll
    for (int dt = 0; dt < 2; ++dt)
#pragma unroll
      for (int jh = 0; jh < 2; ++jh) {
        const int row = dt * 16 + lr;
        const int sw = (row & 7) << 3;
        vf[dt][jh].q.lo = *(const unsigned long long*)&Vs[cur][row * 64 + ((jh * 32 + 4 * g) ^ sw)];
        vf[dt][jh].q.hi = *(const unsigned long long*)&Vs[cur][row * 64 + ((jh * 32 + 16 + 4 * g) ^ sw)];
      }
    f32x4 mf[4];
#pragma unroll
    for (int jt = 0; jt < 4; ++jt) mf[jt] = *(const f32x4*)(&maskadd[cur][jt * 16 + 4 * g]);

    f32x4 sT[4];
#pragma unroll
    for (int jt = 0; jt < 4; ++jt)
      sT[jt] = __builtin_amdgcn_mfma_f32_16x16x32_bf16(kf[jt].v, qf.v, z4, 0, 0, 0);

    float p[4][4];
    const int dlt = kvbase - qw0;
    if (dlt >= 32 || dlt <= -80) {
      const float badd = (dlt > 0) ? bias_hi : bias_lo;
#pragma unroll
      for (int jt = 0; jt < 4; ++jt)
#pragma unroll
        for (int r = 0; r < 4; ++r) p[jt][r] = sT[jt][r] + badd + mf[jt][r];
    } else {
#pragma unroll
      for (int jt = 0; jt < 4; ++jt)
#pragma unroll
        for (int r = 0; r < 4; ++r) {
          int rel = kvbase + jt * 16 + 4 * g + r - (qw0 + lr);
          rel = rel < -16 ? -16 : (rel > 16 ? 16 : rel);
          p[jt][r] = sT[jt][r] + biasv[rel + 16] + mf[jt][r];
        }
    }
    float mloc = -3e38f;
#pragma unroll
    for (int jt = 0; jt < 4; ++jt)
#pragma unroll
      for (int r = 0; r < 4; ++r) mloc = fmaxf(mloc, p[jt][r]);
    mloc = fmaxf(mloc, __shfl_xor(mloc, 16));
    mloc = fmaxf(mloc, __shfl_xor(mloc, 32));
    float m_new = m_run;
    if (!__all(mloc <= m_run + 8.f)) {      // defer-max (T13)
      m_new = fmaxf(m_run, mloc);
      const float corr = fexp2(m_run - m_new);
#pragma unroll
      for (int r = 0; r < 4; ++r) {
        const float c = __shfl(corr, 4 * g + r);
        O0[r] *= c; O1[r] *= c;
      }
      ssum *= corr;
      m_run = m_new;
    }
    float psum = 0.f;
#pragma unroll
    for (int jt = 0; jt < 4; ++jt)
#pragma unroll
      for (int r = 0; r < 4; ++r) {
        const float e = fexp2(p[jt][r] - m_new);
        p[jt][r] = e; psum += e;
      }
    psum += __shfl_xor(psum, 16);
    psum += __shfl_xor(psum, 32);
    ssum += psum;

    FragU a0, a1;                            // T12: packed bf16 convert
    a0.u[0] = cvt_pk_bf16(p[0][0], p[0][1]);
    a0.u[1] = cvt_pk_bf16(p[0][2], p[0][3]);
    a0.u[2] = cvt_pk_bf16(p[1][0], p[1][1]);
    a0.u[3] = cvt_pk_bf16(p[1][2], p[1][3]);
    a1.u[0] = cvt_pk_bf16(p[2][0], p[2][1]);
    a1.u[1] = cvt_pk_bf16(p[2][2], p[2][3]);
    a1.u[2] = cvt_pk_bf16(p[3][0], p[3][1]);
    a1.u[3] = cvt_pk_bf16(p[3][2], p[3][3]);

    O0 = __builtin_amdgcn_mfma_f32_16x16x32_bf16(a0.v, vf[0][0].v, O0, 0, 0, 0);
    O0 = __builtin_amdgcn_mfma_f32_16x16x32_bf16(a1.v, vf[0][1].v, O0, 0, 0, 0);
    O1 = __builtin_amdgcn_mfma_f32_16x16x32_bf16(a0.v, vf[1][0].v, O1, 0, 0, 0);
    O1 = __builtin_amdgcn_mfma_f32_16x16x32_bf16(a1.v, vf[1][1].v, O1, 0, 0, 0);

    // ---- write-late staging for chunk ch+1, then single barrier ----
    if (more) {
      *(int4*)&Ks[nxt][krow * 40 + kc8 * 8] = kreg;
      if (tid < 64) maskadd[nxt][tid] = mreg ? -1e9f : 0.f;
    }
    __syncthreads();
  }

#pragma unroll
  for (int r = 0; r < 4; ++r) {
    const float sden = __shfl(ssum, 4 * g + r);
    const float inv = 1.f / sden;
    const int qo = qw0 + 4 * g + r;
    unsigned short* orow = aout + ((size_t)(b * L_ + qo)) * D_ + h * DH_;
    orow[lr]      = f2bf(O0[r] * inv);
    orow[16 + lr] = f2bf(O1[r] * inv);
  }
}

// ---------------- launch ----------------
extern "C" void kernel_launch(void* const* d_in, const int* in_sizes, int n_in,
                              void* d_out, int out_size, void* d_ws, size_t ws_size,
                              hipStream_t stream) {
  (void)in_sizes; (void)n_in; (void)out_size; (void)ws_size;
  const float* x    = (const float*)d_in[0];
  const int*   mask = (const int*)d_in[1];
  const float* Wqkv = (const float*)d_in[2];
  const float* bqkv = (const float*)d_in[3];
  const float* Wo   = (const float*)d_in[4];
  const float* bo   = (const float*)d_in[5];
  const float* ln1g = (const float*)d_in[6];
  const float* ln1b = (const float*)d_in[7];
  const float* W1   = (const float*)d_in[8];
  const float* b1   = (const float*)d_in[9];
  const float* W2   = (const float*)d_in[10];
  const float* b2   = (const float*)d_in[11];
  const float* ln2g = (const float*)d_in[12];
  const float* ln2b = (const float*)d_in[13];
  const float* relb = (const float*)d_in[14];

  size_t off = 0;
  char* wsb = (char*)d_ws;
  auto carve = [&](size_t bytes) -> void* {
    void* p = wsb + off;
    off += (bytes + 255) & ~(size_t)255;
    return p;
  };
  const size_t tokb = (size_t)B_ * L_;
  unsigned short* xb    = (unsigned short*)carve(tokb * D_ * 2);
  unsigned short* qb    = (unsigned short*)carve(tokb * D_ * 2);
  unsigned short* kbuf  = (unsigned short*)carve(tokb * D_ * 2);
  unsigned short* vTb   = (unsigned short*)carve(tokb * D_ * 2);
  unsigned short* attnb = (unsigned short*)carve(tokb * D_ * 2);
  unsigned short* wqkvt = (unsigned short*)carve((size_t)3 * D_ * D_ * 2);
  unsigned short* wot   = (unsigned short*)carve((size_t)D_ * D_ * 2);
  unsigned short* w1t   = (unsigned short*)carve((size_t)D_ * MLP_ * 2);
  unsigned short* w2t   = (unsigned short*)carve((size_t)D_ * MLP_ * 2);
  float*          x1    = (float*)carve(tokb * D_ * 4);
  unsigned short* x1b   = (unsigned short*)carve(tokb * D_ * 2);
  unsigned short* hbuf  = (unsigned short*)carve(tokb * MLP_ * 2);

  cvt_k<<<(tokb * D_ / 4 + 255) / 256, 256, 0, stream>>>(x, xb, (int)(tokb * D_ / 4));
  prep_w<<<3072, 256, 0, stream>>>(Wqkv, Wo, W1, W2, wqkvt, wot, w1t, w2t);

  gemm_k<0, 64, 128><<<dim3(3 * D_ / 128, tokb / 64), 256, 0, stream>>>(
      xb, wqkvt, bqkv, qb, kbuf, vTb, D_);
  attn_k<<<dim3(L_ / 64, B_ * H_), 256, 0, stream>>>(qb, kbuf, vTb, mask, relb, attnb);
  gemmln_k<true><<<tokb / 32, 512, 0, stream>>>(
      attnb, wot, bo, x, ln1g, ln1b, x1, x1b, D_);
  gemm_k<2, 64, 128><<<dim3(MLP_ / 128, tokb / 64), 256, 0, stream>>>(
      x1b, w1t, b1, hbuf, nullptr, nullptr, D_);
  gemmln_k<false><<<tokb / 32, 512, 0, stream>>>(
      hbuf, w2t, b2, x1, ln2g, ln2b, (float*)d_out, nullptr, MLP_);
}

// Round 6
// 132.357 us; speedup vs baseline: 1.1714x; 1.1714x over previous
//
#include <hip/hip_runtime.h>

#define B_   4
#define L_   2048
#define D_   256
#define H_   8
#define DH_  32
#define MLP_ 1024
#define LOG2E 1.4426950408889634f

typedef __attribute__((ext_vector_type(8))) short  short8;
typedef __attribute__((ext_vector_type(4))) float  f32x4;
typedef unsigned long long ull;

union FragU { short8 v; struct { ull lo, hi; } q; unsigned u[4]; };

__device__ __forceinline__ unsigned short f2bf(float f) {
  unsigned u = __float_as_uint(f);
  u += 0x7fffu + ((u >> 16) & 1u);
  return (unsigned short)(u >> 16);
}

__device__ __forceinline__ ull pack4(float a, float b, float c, float d) {
  return (ull)f2bf(a) | ((ull)f2bf(b) << 16) | ((ull)f2bf(c) << 32) | ((ull)f2bf(d) << 48);
}

__device__ __forceinline__ unsigned cvt_pk_bf16(float lo, float hi) {
  unsigned r;
  asm("v_cvt_pk_bf16_f32 %0, %1, %2" : "=v"(r) : "v"(lo), "v"(hi));
  return r;
}

__device__ __forceinline__ float fexp2(float x) {
#if __has_builtin(__builtin_amdgcn_exp2f)
  return __builtin_amdgcn_exp2f(x);
#else
  return exp2f(x);
#endif
}

#define GLL16(gp, lp) __builtin_amdgcn_global_load_lds( \
    (const __attribute__((address_space(1))) void*)(gp), \
    (__attribute__((address_space(3))) void*)(lp), 16, 0, 0)

// ---------------- input conversions, one launch ----------------
__global__ void prep_w(const float* __restrict__ x,
                       const float* __restrict__ Wqkv, const float* __restrict__ Wo,
                       const float* __restrict__ W1, const float* __restrict__ W2,
                       unsigned short* __restrict__ xb,
                       unsigned short* __restrict__ wqkvt, unsigned short* __restrict__ wot,
                       unsigned short* __restrict__ w1t, unsigned short* __restrict__ w2t) {
  const int i = blockIdx.x * 256 + threadIdx.x;
  if (i < 131072) {            // x: 2M floats, 4 per thread
    const float4 v = *(const float4*)(x + (size_t)i * 4);
    *(ull*)(xb + (size_t)i * 4) = pack4(v.x, v.y, v.z, v.w);
  } else if (i < 327680) {     // Wqkv 256x768
    const int j = i - 131072, r = j / 768, c = j - r * 768;
    wqkvt[(size_t)c * 256 + r] = f2bf(Wqkv[j]);
  } else if (i < 393216) {     // Wo 256x256
    const int j = i - 327680, r = j >> 8, c = j & 255;
    wot[(size_t)c * 256 + r] = f2bf(Wo[j]);
  } else if (i < 655360) {     // W1 256x1024
    const int j = i - 393216, r = j >> 10, c = j & 1023;
    w1t[(size_t)c * 256 + r] = f2bf(W1[j]);
  } else {                     // W2 1024x256
    const int j = i - 655360, r = j >> 8, c = j & 255;
    w2t[(size_t)c * 1024 + r] = f2bf(W2[j]);
  }
}

// ---------------- GEMM (dbuf, counted vmcnt): C = A * Bt^T + bias ----------------
template <int MODE, int TM, int TN>
__launch_bounds__(256)
__global__ void gemm_k(const unsigned short* __restrict__ A,
                       const unsigned short* __restrict__ Bt,
                       const float* __restrict__ bias,
                       unsigned short* __restrict__ outb0,
                       unsigned short* __restrict__ outb1,
                       unsigned short* __restrict__ outb2,
                       int K)
{
  constexpr int MI = TM / 32, NI = TN / 32;
  __shared__ alignas(16) unsigned short As[2][TM * 64];
  __shared__ alignas(16) unsigned short Bs[2][TN * 64];
  const int tid  = threadIdx.x;
  const int lane = tid & 63, wv = tid >> 6;
  const int wr = wv >> 1, wc = wv & 1;
  const int lr = lane & 15, g = lane >> 4;
  const int m0 = blockIdx.y * TM, n0 = blockIdx.x * TN;
  const int l8 = lane >> 3, jj = lane & 7;

  auto stage = [&](int buf, int k0) {
#pragma unroll
    for (int i = 0; i < MI; ++i) {
      const int row = i * 32 + wv * 8 + l8;
      GLL16(A + (size_t)(m0 + row) * K + k0 + ((jj ^ (row & 7)) * 8),
            &As[buf][i * 2048 + wv * 512]);
    }
#pragma unroll
    for (int i = 0; i < NI; ++i) {
      const int row = i * 32 + wv * 8 + l8;
      GLL16(Bt + (size_t)(n0 + row) * K + k0 + ((jj ^ (row & 7)) * 8),
            &Bs[buf][i * 2048 + wv * 512]);
    }
  };

  f32x4 acc[MI][NI];
#pragma unroll
  for (int i = 0; i < MI; ++i)
#pragma unroll
    for (int j = 0; j < NI; ++j) acc[i][j] = (f32x4)(0.f);

  stage(0, 0);
  for (int k0 = 0; k0 < K; k0 += 64) {
    const int cur = (k0 >> 6) & 1;
    if (k0 + 64 < K) {
      stage(cur ^ 1, k0 + 64);
      asm volatile("s_waitcnt vmcnt(%0)" :: "n"(MI + NI) : "memory");
    } else {
      asm volatile("s_waitcnt vmcnt(0)" ::: "memory");
    }
    __builtin_amdgcn_sched_barrier(0);
    __builtin_amdgcn_s_barrier();
#pragma unroll
    for (int kk = 0; kk < 2; ++kk) {
      FragU af[MI], bf[NI];
#pragma unroll
      for (int mi = 0; mi < MI; ++mi) {
        const int row = wr * (TM / 2) + mi * 16 + lr;
        const int sw = (row & 7) << 3;
        af[mi].q.lo = *(const ull*)&As[cur][row * 64 + ((kk * 32 + 4 * g) ^ sw)];
        af[mi].q.hi = *(const ull*)&As[cur][row * 64 + ((kk * 32 + 16 + 4 * g) ^ sw)];
      }
#pragma unroll
      for (int ni = 0; ni < NI; ++ni) {
        const int row = wc * (TN / 2) + ni * 16 + lr;
        const int sw = (row & 7) << 3;
        bf[ni].q.lo = *(const ull*)&Bs[cur][row * 64 + ((kk * 32 + 4 * g) ^ sw)];
        bf[ni].q.hi = *(const ull*)&Bs[cur][row * 64 + ((kk * 32 + 16 + 4 * g) ^ sw)];
      }
#pragma unroll
      for (int mi = 0; mi < MI; ++mi)
#pragma unroll
        for (int ni = 0; ni < NI; ++ni)
          acc[mi][ni] = __builtin_amdgcn_mfma_f32_16x16x32_bf16(af[mi].v, bf[ni].v, acc[mi][ni], 0, 0, 0);
    }
    asm volatile("s_waitcnt lgkmcnt(0)" ::: "memory");
    __builtin_amdgcn_sched_barrier(0);
    __builtin_amdgcn_s_barrier();
  }

#pragma unroll
  for (int mi = 0; mi < MI; ++mi) {
#pragma unroll
    for (int ni = 0; ni < NI; ++ni) {
      const int n = n0 + wc * (TN / 2) + ni * 16 + lr;
      const float bv = bias[n];
#pragma unroll
      for (int r = 0; r < 4; ++r) {
        const int m = m0 + wr * (TM / 2) + mi * 16 + 4 * g + r;
        float val = acc[mi][ni][r] + bv;
        if constexpr (MODE == 0) {
          const int s = n >> 8, hh = (n >> 5) & 7, dh = n & 31;
          const int bb = m >> 11, l = m & (L_ - 1);
          if (s == 0) {
            outb0[((size_t)(bb * H_ + hh) * L_ + l) * DH_ + dh] =
                f2bf(val * (0.17677669529663687f * LOG2E));
          } else if (s == 1) {
            outb1[((size_t)(bb * H_ + hh) * L_ + l) * DH_ + dh] = f2bf(val);
          } else {
            outb2[((size_t)(bb * H_ + hh) * DH_ + dh) * L_ + l] = f2bf(val);
          }
        } else {
          outb0[(size_t)m * MLP_ + n] = f2bf(fmaxf(val, 0.f));
        }
      }
    }
  }
}

// ---------------- fused GEMM + residual + LayerNorm (full row TN=256) ----------------
template <bool WRITE_BF>
__launch_bounds__(512)
__global__ void gemmln_k(const unsigned short* __restrict__ A,
                         const unsigned short* __restrict__ Bt,
                         const float* __restrict__ bias,
                         const float* __restrict__ resid,
                         const float* __restrict__ lng,
                         const float* __restrict__ lnb,
                         float* __restrict__ outf,
                         unsigned short* __restrict__ outb,
                         int K)
{
  __shared__ alignas(16) unsigned short As[2][32 * 64];
  __shared__ alignas(16) unsigned short Bs[2][256 * 64];
  __shared__ float rsum[8][16], rsq[8][16], rmu[32], rrstd[32];
  const int tid  = threadIdx.x;
  const int lane = tid & 63, wv = tid >> 6;
  const int wr = wv >> 2, wc = wv & 3;
  const int lr = lane & 15, g = lane >> 4;
  const int m0 = blockIdx.x * 32;
  const int l8 = lane >> 3, jj = lane & 7;

  auto stage = [&](int buf, int k0) {
    if (wv < 4) {
      const int row = wv * 8 + l8;
      GLL16(A + (size_t)(m0 + row) * K + k0 + ((jj ^ (row & 7)) * 8),
            &As[buf][wv * 512]);
    }
#pragma unroll
    for (int i = 0; i < 4; ++i) {
      const int n = i * 64 + wv * 8 + l8;
      GLL16(Bt + (size_t)n * K + k0 + ((jj ^ (n & 7)) * 8),
            &Bs[buf][i * 4096 + wv * 512]);
    }
  };

  f32x4 acc[4];
#pragma unroll
  for (int j = 0; j < 4; ++j) acc[j] = (f32x4)(0.f);

  stage(0, 0);
  for (int k0 = 0; k0 < K; k0 += 64) {
    const int cur = (k0 >> 6) & 1;
    if (k0 + 64 < K) {
      stage(cur ^ 1, k0 + 64);
      asm volatile("s_waitcnt vmcnt(4)" ::: "memory");
    } else {
      asm volatile("s_waitcnt vmcnt(0)" ::: "memory");
    }
    __builtin_amdgcn_sched_barrier(0);
    __builtin_amdgcn_s_barrier();
#pragma unroll
    for (int kk = 0; kk < 2; ++kk) {
      FragU af, bf[4];
      {
        const int row = wr * 16 + lr;
        const int sw = (row & 7) << 3;
        af.q.lo = *(const ull*)&As[cur][row * 64 + ((kk * 32 + 4 * g) ^ sw)];
        af.q.hi = *(const ull*)&As[cur][row * 64 + ((kk * 32 + 16 + 4 * g) ^ sw)];
      }
#pragma unroll
      for (int ni = 0; ni < 4; ++ni) {
        const int row = wc * 64 + ni * 16 + lr;
        const int sw = (row & 7) << 3;
        bf[ni].q.lo = *(const ull*)&Bs[cur][row * 64 + ((kk * 32 + 4 * g) ^ sw)];
        bf[ni].q.hi = *(const ull*)&Bs[cur][row * 64 + ((kk * 32 + 16 + 4 * g) ^ sw)];
      }
#pragma unroll
      for (int ni = 0; ni < 4; ++ni)
        acc[ni] = __builtin_amdgcn_mfma_f32_16x16x32_bf16(af.v, bf[ni].v, acc[ni], 0, 0, 0);
    }
    asm volatile("s_waitcnt lgkmcnt(0)" ::: "memory");
    __builtin_amdgcn_sched_barrier(0);
    __builtin_amdgcn_s_barrier();
  }

  float g4[4], b4[4], bias4[4];
  int col[4];
#pragma unroll
  for (int ni = 0; ni < 4; ++ni) {
    col[ni] = wc * 64 + ni * 16 + lr;
    g4[ni] = lng[col[ni]]; b4[ni] = lnb[col[ni]]; bias4[ni] = bias[col[ni]];
  }
  float vals[4][4];
#pragma unroll
  for (int r = 0; r < 4; ++r) {
    const int row = wr * 16 + 4 * g + r;
    float s = 0.f, q = 0.f;
#pragma unroll
    for (int ni = 0; ni < 4; ++ni) {
      float v = acc[ni][r] + bias4[ni] + resid[(size_t)(m0 + row) * D_ + col[ni]];
      vals[ni][r] = v; s += v; q += v * v;
    }
#pragma unroll
    for (int off = 1; off < 16; off <<= 1) {
      s += __shfl_xor(s, off); q += __shfl_xor(q, off);
    }
    if (lr == 0) { rsum[wv][4 * g + r] = s; rsq[wv][4 * g + r] = q; }
  }
  __syncthreads();
  if (tid < 32) {
    const int base = (tid >> 4) * 4, rr = tid & 15;
    const float s = rsum[base][rr] + rsum[base + 1][rr] + rsum[base + 2][rr] + rsum[base + 3][rr];
    const float q = rsq[base][rr] + rsq[base + 1][rr] + rsq[base + 2][rr] + rsq[base + 3][rr];
    const float mu = s * (1.f / D_);
    rmu[tid] = mu;
    rrstd[tid] = rsqrtf(q * (1.f / D_) - mu * mu + 1e-5f);
  }
  __syncthreads();
#pragma unroll
  for (int r = 0; r < 4; ++r) {
    const int row = wr * 16 + 4 * g + r;
    const float mu = rmu[row], rs = rrstd[row];
#pragma unroll
    for (int ni = 0; ni < 4; ++ni) {
      const float o = (vals[ni][r] - mu) * rs * g4[ni] + b4[ni];
      const size_t idx = (size_t)(m0 + row) * D_ + col[ni];
      outf[idx] = o;
      if constexpr (WRITE_BF) outb[idx] = f2bf(o);
    }
  }
}

// ---------------- flash attention: KV chunk 128 (2x64 sub-tiles), full dbuf,
// one barrier per chunk ----------------
__launch_bounds__(256)
__global__ void attn_k(const unsigned short* __restrict__ qb,
                       const unsigned short* __restrict__ kp,
                       const unsigned short* __restrict__ vT,
                       const int* __restrict__ mask,
                       const float* __restrict__ relb,
                       unsigned short* __restrict__ aout)
{
  __shared__ alignas(16) unsigned short Ks[2][128 * 40];   // padded rows (80B): 2-way free
  __shared__ alignas(16) unsigned short Vs[2][32 * 128];   // XOR-swizzled (gll16 pre-swz source)
  __shared__ alignas(16) float biasv[36];
  __shared__ alignas(16) float maskadd[2][128];
  const int tid = threadIdx.x;
  const int lane = tid & 63, wv = tid >> 6;
  const int lr = lane & 15, g = lane >> 4;
  const int bh = blockIdx.y, b = bh >> 3, h = bh & 7;
  const size_t bhoff = (size_t)bh * (L_ * DH_);
  if (tid < 33) biasv[tid] = relb[tid * H_ + h] * LOG2E;
  const float bias_lo = relb[h] * LOG2E;
  const float bias_hi = relb[32 * H_ + h] * LOG2E;
  const int qw0 = blockIdx.x * 64 + wv * 16;

  FragU qf;
  {
    const unsigned short* qr = qb + bhoff + (size_t)(qw0 + lr) * DH_;
    qf.q.lo = *(const ull*)(qr + 4 * g);
    qf.q.hi = *(const ull*)(qr + 16 + 4 * g);
  }
  f32x4 O0 = (f32x4)(0.f), O1 = (f32x4)(0.f);
  float m_run = -1e30f, ssum = 0.f;
  const f32x4 z4 = (f32x4)(0.f);
  const int krow = tid >> 1, koff = (tid & 1) * 16;   // 128 K-rows, 2 threads/row

  // prologue: stage chunk 0 into buffers[0]
  {
    const unsigned short* ksrc = kp + bhoff + (size_t)krow * DH_ + koff;
    const int4 ka = *(const int4*)ksrc;
    const int4 kc = *(const int4*)(ksrc + 8);
#pragma unroll
    for (int i = 0; i < 2; ++i) {
      const int d = (wv * 2 + i) * 4 + (lane >> 4);
      GLL16(vT + ((size_t)bh * DH_ + d) * L_ + (((lane & 15) * 8) ^ ((d & 7) * 8)),
            &Vs[0][(wv * 2 + i) * 512]);
    }
    const int mreg = (tid < 128) ? mask[b * L_ + tid] : 0;
    *(int4*)&Ks[0][krow * 40 + koff] = ka;
    *(int4*)&Ks[0][krow * 40 + koff + 8] = kc;
    if (tid < 128) maskadd[0][tid] = mreg ? -1e9f : 0.f;
    asm volatile("s_waitcnt vmcnt(0) lgkmcnt(0)" ::: "memory");
    __builtin_amdgcn_s_barrier();
  }

#pragma unroll 2
  for (int ch = 0; ch < 16; ++ch) {
    const int cur = ch & 1, nxt = cur ^ 1;
    const int kv = ch * 128;
    const bool more = ch < 15;
    int4 ka = {0, 0, 0, 0}, kc = {0, 0, 0, 0};
    int mreg = 0;
    if (more) {   // prefetch chunk ch+1: K->regs, V->LDS[nxt] via gll16, mask->reg
      const unsigned short* ksrc = kp + bhoff + (size_t)(kv + 128 + krow) * DH_ + koff;
      ka = *(const int4*)ksrc;
      kc = *(const int4*)(ksrc + 8);
#pragma unroll
      for (int i = 0; i < 2; ++i) {
        const int d = (wv * 2 + i) * 4 + (lane >> 4);
        GLL16(vT + ((size_t)bh * DH_ + d) * L_ + kv + 128 + (((lane & 15) * 8) ^ ((d & 7) * 8)),
              &Vs[nxt][(wv * 2 + i) * 512]);
      }
      if (tid < 128) mreg = mask[b * L_ + kv + 128 + tid];
    }

#pragma unroll
    for (int st = 0; st < 2; ++st) {
      const int j0 = kv + st * 64;
      const unsigned short* KsC = &Ks[cur][st * 64 * 40];
      FragU kf[4];
#pragma unroll
      for (int jt = 0; jt < 4; ++jt) {
        const int base = (jt * 16 + lr) * 40;
        kf[jt].q.lo = *(const ull*)&KsC[base + 4 * g];
        kf[jt].q.hi = *(const ull*)&KsC[base + 16 + 4 * g];
      }
      f32x4 sT[4];
#pragma unroll
      for (int jt = 0; jt < 4; ++jt)
        sT[jt] = __builtin_amdgcn_mfma_f32_16x16x32_bf16(kf[jt].v, qf.v, z4, 0, 0, 0);

      float p[4][4];
      const int dlt = j0 - qw0;
      if (dlt >= 32 || dlt <= -80) {          // entire sub-tile beyond the +-16 ramp
        const float ba = (dlt > 0) ? bias_hi : bias_lo;
#pragma unroll
        for (int jt = 0; jt < 4; ++jt)
#pragma unroll
          for (int r = 0; r < 4; ++r)
            p[jt][r] = sT[jt][r] + ba + maskadd[cur][st * 64 + jt * 16 + 4 * g + r];
      } else {
#pragma unroll
        for (int jt = 0; jt < 4; ++jt)
#pragma unroll
          for (int r = 0; r < 4; ++r) {
            int rel = j0 + jt * 16 + 4 * g + r - (qw0 + lr);
            rel = rel < -16 ? -16 : (rel > 16 ? 16 : rel);
            p[jt][r] = sT[jt][r] + biasv[rel + 16] + maskadd[cur][st * 64 + jt * 16 + 4 * g + r];
          }
      }
      float mloc = -3e38f;
#pragma unroll
      for (int jt = 0; jt < 4; ++jt)
#pragma unroll
        for (int r = 0; r < 4; ++r) mloc = fmaxf(mloc, p[jt][r]);
      mloc = fmaxf(mloc, __shfl_xor(mloc, 16));
      mloc = fmaxf(mloc, __shfl_xor(mloc, 32));
      float m_new = m_run;
      if (!__all(mloc <= m_run + 8.f)) {      // defer-max (T13)
        m_new = fmaxf(m_run, mloc);
        const float corr = fexp2(m_run - m_new);
#pragma unroll
        for (int r = 0; r < 4; ++r) {
          const float c = __shfl(corr, 4 * g + r);
          O0[r] *= c; O1[r] *= c;
        }
        ssum *= corr;
        m_run = m_new;
      }
      float psum = 0.f;
#pragma unroll
      for (int jt = 0; jt < 4; ++jt)
#pragma unroll
        for (int r = 0; r < 4; ++r) {
          const float e = fexp2(p[jt][r] - m_new);
          p[jt][r] = e; psum += e;
        }
      psum += __shfl_xor(psum, 16);
      psum += __shfl_xor(psum, 32);
      ssum += psum;

      FragU a0, a1;                            // T12: packed bf16 convert
      a0.u[0] = cvt_pk_bf16(p[0][0], p[0][1]);
      a0.u[1] = cvt_pk_bf16(p[0][2], p[0][3]);
      a0.u[2] = cvt_pk_bf16(p[1][0], p[1][1]);
      a0.u[3] = cvt_pk_bf16(p[1][2], p[1][3]);
      a1.u[0] = cvt_pk_bf16(p[2][0], p[2][1]);
      a1.u[1] = cvt_pk_bf16(p[2][2], p[2][3]);
      a1.u[2] = cvt_pk_bf16(p[3][0], p[3][1]);
      a1.u[3] = cvt_pk_bf16(p[3][2], p[3][3]);

      FragU vf00, vf01, vf10, vf11;
#pragma unroll
      for (int dt = 0; dt < 2; ++dt) {
        const int row = dt * 16 + lr;
        const int sw = (row & 7) << 3;
        FragU v0, v1;
        v0.q.lo = *(const ull*)&Vs[cur][row * 128 + ((st * 64 + 4 * g) ^ sw)];
        v0.q.hi = *(const ull*)&Vs[cur][row * 128 + ((st * 64 + 16 + 4 * g) ^ sw)];
        v1.q.lo = *(const ull*)&Vs[cur][row * 128 + ((st * 64 + 32 + 4 * g) ^ sw)];
        v1.q.hi = *(const ull*)&Vs[cur][row * 128 + ((st * 64 + 48 + 4 * g) ^ sw)];
        if (dt == 0) { vf00 = v0; vf01 = v1; } else { vf10 = v0; vf11 = v1; }
      }
      O0 = __builtin_amdgcn_mfma_f32_16x16x32_bf16(a0.v, vf00.v, O0, 0, 0, 0);
      O0 = __builtin_amdgcn_mfma_f32_16x16x32_bf16(a1.v, vf01.v, O0, 0, 0, 0);
      O1 = __builtin_amdgcn_mfma_f32_16x16x32_bf16(a0.v, vf10.v, O1, 0, 0, 0);
      O1 = __builtin_amdgcn_mfma_f32_16x16x32_bf16(a1.v, vf11.v, O1, 0, 0, 0);
    }

    if (more) {  // write-late K/mask into next buffers (not read by anyone yet)
      *(int4*)&Ks[nxt][krow * 40 + koff] = ka;
      *(int4*)&Ks[nxt][krow * 40 + koff + 8] = kc;
      if (tid < 128) maskadd[nxt][tid] = mreg ? -1e9f : 0.f;
    }
    asm volatile("s_waitcnt vmcnt(0) lgkmcnt(0)" ::: "memory");
    __builtin_amdgcn_sched_barrier(0);
    __builtin_amdgcn_s_barrier();
  }

#pragma unroll
  for (int r = 0; r < 4; ++r) {
    const float sden = __shfl(ssum, 4 * g + r);
    const float inv = 1.f / sden;
    const int qo = qw0 + 4 * g + r;
    unsigned short* orow = aout + ((size_t)(b * L_ + qo)) * D_ + h * DH_;
    orow[lr]      = f2bf(O0[r] * inv);
    orow[16 + lr] = f2bf(O1[r] * inv);
  }
}

// ---------------- launch ----------------
extern "C" void kernel_launch(void* const* d_in, const int* in_sizes, int n_in,
                              void* d_out, int out_size, void* d_ws, size_t ws_size,
                              hipStream_t stream) {
  (void)in_sizes; (void)n_in; (void)out_size; (void)ws_size;
  const float* x    = (const float*)d_in[0];
  const int*   mask = (const int*)d_in[1];
  const float* Wqkv = (const float*)d_in[2];
  const float* bqkv = (const float*)d_in[3];
  const float* Wo   = (const float*)d_in[4];
  const float* bo   = (const float*)d_in[5];
  const float* ln1g = (const float*)d_in[6];
  const float* ln1b = (const float*)d_in[7];
  const float* W1   = (const float*)d_in[8];
  const float* b1   = (const float*)d_in[9];
  const float* W2   = (const float*)d_in[10];
  const float* b2   = (const float*)d_in[11];
  const float* ln2g = (const float*)d_in[12];
  const float* ln2b = (const float*)d_in[13];
  const float* relb = (const float*)d_in[14];

  size_t off = 0;
  char* wsb = (char*)d_ws;
  auto carve = [&](size_t bytes) -> void* {
    void* p = wsb + off;
    off += (bytes + 255) & ~(size_t)255;
    return p;
  };
  const size_t tokb = (size_t)B_ * L_;
  unsigned short* xb    = (unsigned short*)carve(tokb * D_ * 2);
  unsigned short* qbuf  = (unsigned short*)carve(tokb * D_ * 2);
  unsigned short* kbuf  = (unsigned short*)carve(tokb * D_ * 2);
  unsigned short* vTb   = (unsigned short*)carve(tokb * D_ * 2);
  unsigned short* attnb = (unsigned short*)carve(tokb * D_ * 2);
  unsigned short* wqkvt = (unsigned short*)carve((size_t)3 * D_ * D_ * 2);
  unsigned short* wot   = (unsigned short*)carve((size_t)D_ * D_ * 2);
  unsigned short* w1t   = (unsigned short*)carve((size_t)D_ * MLP_ * 2);
  unsigned short* w2t   = (unsigned short*)carve((size_t)D_ * MLP_ * 2);
  float*          x1    = (float*)carve(tokb * D_ * 4);
  unsigned short* x1b   = (unsigned short*)carve(tokb * D_ * 2);
  unsigned short* hbuf  = (unsigned short*)carve(tokb * MLP_ * 2);

  prep_w<<<3584, 256, 0, stream>>>(x, Wqkv, Wo, W1, W2, xb, wqkvt, wot, w1t, w2t);

  gemm_k<0, 64, 128><<<dim3(3 * D_ / 128, tokb / 64), 256, 0, stream>>>(
      xb, wqkvt, bqkv, qbuf, kbuf, vTb, D_);
  attn_k<<<dim3(L_ / 64, B_ * H_), 256, 0, stream>>>(qbuf, kbuf, vTb, mask, relb, attnb);
  gemmln_k<true><<<tokb / 32, 512, 0, stream>>>(
      attnb, wot, bo, x, ln1g, ln1b, x1, x1b, D_);
  gemm_k<2, 64, 128><<<dim3(MLP_ / 128, tokb / 64), 256, 0, stream>>>(
      x1b, w1t, b1, hbuf, nullptr, nullptr, D_);
  gemmln_k<false><<<tokb / 32, 512, 0, stream>>>(
      hbuf, w2t, b2, x1, ln2g, ln2b, (float*)d_out, nullptr, MLP_);
}